// Round 2
// baseline (40.298 us; speedup 1.0000x reference)
//
#include <hip/hip_runtime.h>
#include <math.h>

#define BLK 256
#define SLICE 512   // target points staged per block (6 KB LDS)

__device__ __forceinline__ float d2f(float sx, float sy, float sz,
                                     float tx, float ty, float tz) {
    float dx = sx - tx, dy = sy - ty, dz = sz - tz;
    return fmaf(dz, dz, fmaf(dy, dy, dx * dx));
}

// grid: (ceil(maxN/BLK), ceil(maxN/SLICE), 2). Each block: 256 src points
// (one per thread, in registers) vs one SLICE of targets (staged in LDS,
// broadcast-read). Per-src-point min d^2 combined across slices via uint
// atomicMin (bit pattern of non-negative float is order-preserving).
__global__ void hd_min_kernel(const float* __restrict__ s1, int n1,
                              const float* __restrict__ s2, int n2,
                              unsigned int* __restrict__ min1,
                              unsigned int* __restrict__ min2) {
    const int dir = blockIdx.z;
    const float* src = (dir == 0) ? s1 : s2;
    const float* tgt = (dir == 0) ? s2 : s1;
    const int nSrc   = (dir == 0) ? n1 : n2;
    const int nTgt   = (dir == 0) ? n2 : n1;
    unsigned int* mout = (dir == 0) ? min1 : min2;

    const int j0 = blockIdx.y * SLICE;
    if (j0 >= nTgt) return;                    // uniform across block
    if (blockIdx.x * BLK >= nSrc) return;      // uniform across block
    const int cnt = min(SLICE, nTgt - j0);

    __shared__ float lds[SLICE * 3];

    // stage slice: cnt*3 floats, float4-vectorized (j0*12 bytes is 16B-aligned)
    {
        const float*  g  = tgt + (size_t)j0 * 3;
        const int total  = cnt * 3;
        const int total4 = total >> 2;
        const float4* g4 = (const float4*)g;
        float4* l4 = (float4*)lds;
        for (int t = threadIdx.x; t < total4; t += BLK) l4[t] = g4[t];
        for (int t = (total4 << 2) + threadIdx.x; t < total; t += BLK) lds[t] = g[t];
    }
    __syncthreads();

    const int i = blockIdx.x * BLK + threadIdx.x;
    const bool valid = (i < nSrc);
    float sx = 0.f, sy = 0.f, sz = 0.f;
    if (valid) {
        sx = src[(size_t)i * 3 + 0];
        sy = src[(size_t)i * 3 + 1];
        sz = src[(size_t)i * 3 + 2];
    }

    float m0 = INFINITY, m1 = INFINITY, m2 = INFINITY, m3 = INFINITY;
    const int nc = cnt >> 2;                   // chunks of 4 target points
    const float4* l4 = (const float4*)lds;
    #pragma unroll 4
    for (int c = 0; c < nc; ++c) {
        float4 a = l4[3 * c + 0];
        float4 b = l4[3 * c + 1];
        float4 d = l4[3 * c + 2];
        m0 = fminf(m0, d2f(sx, sy, sz, a.x, a.y, a.z));
        m1 = fminf(m1, d2f(sx, sy, sz, a.w, b.x, b.y));
        m2 = fminf(m2, d2f(sx, sy, sz, b.z, b.w, d.x));
        m3 = fminf(m3, d2f(sx, sy, sz, d.y, d.z, d.w));
    }
    for (int j = nc << 2; j < cnt; ++j) {      // tail (generic sizes)
        m0 = fminf(m0, d2f(sx, sy, sz, lds[3*j], lds[3*j+1], lds[3*j+2]));
    }
    float m = fminf(fminf(m0, m1), fminf(m2, m3));
    if (valid) atomicMin(mout + i, __float_as_uint(m));
}

// blockIdx.x = direction. Reduce n per-point min-d^2 values -> sum of sqrt, max of sqrt.
__global__ void hd_reduce_kernel(const unsigned int* __restrict__ min1, int n1,
                                 const unsigned int* __restrict__ min2, int n2,
                                 float* __restrict__ results) {
    const int dir = blockIdx.x;
    const unsigned int* mins = (dir == 0) ? min1 : min2;
    const int n = (dir == 0) ? n1 : n2;

    float sum = 0.f, mx = 0.f;
    for (int t = threadIdx.x; t < n; t += BLK) {
        float d = sqrtf(__uint_as_float(mins[t]));
        sum += d;
        mx = fmaxf(mx, d);
    }
    // wave (64-lane) reduce
    for (int o = 32; o > 0; o >>= 1) {
        sum += __shfl_down(sum, o);
        mx = fmaxf(mx, __shfl_down(mx, o));
    }
    __shared__ float ssum[BLK / 64], smax[BLK / 64];
    const int wid = threadIdx.x >> 6, lid = threadIdx.x & 63;
    if (lid == 0) { ssum[wid] = sum; smax[wid] = mx; }
    __syncthreads();
    if (threadIdx.x == 0) {
        float s = 0.f, m = 0.f;
        for (int w = 0; w < BLK / 64; ++w) { s += ssum[w]; m = fmaxf(m, smax[w]); }
        results[dir * 2 + 0] = s;
        results[dir * 2 + 1] = m;
    }
}

__global__ void hd_final_kernel(const float* __restrict__ results,
                                const int* __restrict__ haus,
                                const int* __restrict__ w12,
                                const int* __restrict__ w21,
                                const int* __restrict__ nout,
                                int n1, int n2, float* __restrict__ out) {
    float t12 = 0.f, t21 = 0.f;
    if (*w12 != 0) t12 = (*haus == 0) ? results[0] / (float)n1 : results[1];
    if (*w21 != 0) t21 = (*haus == 0) ? results[2] / (float)n2 : results[3];
    if (*nout == 1) {
        out[0] = t12 + t21;
    } else {
        out[0] = t12;
        out[1] = t21;
    }
}

extern "C" void kernel_launch(void* const* d_in, const int* in_sizes, int n_in,
                              void* d_out, int out_size, void* d_ws, size_t ws_size,
                              hipStream_t stream) {
    const float* s1 = (const float*)d_in[0];
    const float* s2 = (const float*)d_in[1];
    const int* haus = (const int*)d_in[2];
    const int* w12  = (const int*)d_in[3];
    const int* w21  = (const int*)d_in[4];
    const int* nout = (const int*)d_in[5];
    float* out = (float*)d_out;

    const int n1 = in_sizes[0] / 3;
    const int n2 = in_sizes[1] / 3;

    // ws layout: [n1] uint mins dir0 | [n2] uint mins dir1 | 4 floats results
    unsigned int* min1 = (unsigned int*)d_ws;
    unsigned int* min2 = min1 + n1;
    float* results = (float*)(min2 + n2);

    // init mins to 0xFFFFFFFF (max uint) for atomicMin
    hipMemsetAsync(d_ws, 0xFF, (size_t)(n1 + n2) * sizeof(unsigned int), stream);

    const int maxN = (n1 > n2) ? n1 : n2;
    dim3 grid((maxN + BLK - 1) / BLK, (maxN + SLICE - 1) / SLICE, 2);
    hd_min_kernel<<<grid, BLK, 0, stream>>>(s1, n1, s2, n2, min1, min2);

    hd_reduce_kernel<<<2, BLK, 0, stream>>>(min1, n1, min2, n2, results);

    hd_final_kernel<<<1, 1, 0, stream>>>(results, haus, w12, w21, nout, n1, n2, out);
}